// Round 16
// baseline (9432.611 us; speedup 1.0000x reference)
//
#include <hip/hip_runtime.h>
#include <hip/hip_bf16.h>

#define BB 32
#define TT 64
#define NNODE 1024
#define EE 4096
#define NEDGE 5120        // EE + NNODE self loops
#define NHEAD 8
#define HLL 512
#define HRR 64
#define TWO_N 2048
#define KCELL 2560

__device__ __forceinline__ float sigmoidf_(float x){ return 1.f/(1.f+expf(-x)); }
__device__ __forceinline__ float leaky(float x, float s){ return x>0.f? x : s*x; }

// ---------------- CSR by dst (deterministic), packed (src<<13 | eid) ----------------
__global__ __launch_bounds__(1024) void k_csr_off(const int* __restrict__ ei, int* __restrict__ off){
  __shared__ int deg[NNODE];
  __shared__ int scn[NNODE];
  int tid = threadIdx.x;
  deg[tid] = 1;  // self loop
  __syncthreads();
  for(int e=tid; e<EE; e+=1024) atomicAdd(&deg[ei[EE+e]], 1);
  __syncthreads();
  scn[tid] = deg[tid];
  __syncthreads();
  for(int ofs=1; ofs<1024; ofs<<=1){
    int add = (tid>=ofs)? scn[tid-ofs] : 0;
    __syncthreads();
    scn[tid] += add;
    __syncthreads();
  }
  off[tid+1] = scn[tid];
  if(tid==0) off[0] = 0;
}

__global__ __launch_bounds__(1024) void k_csr_fill(const int* __restrict__ ei,
    const int* __restrict__ off, int* __restrict__ adjp){
  __shared__ int dstb[EE];
  int tid = threadIdx.x;
  for(int e=tid; e<EE; e+=1024) dstb[e] = ei[EE+e];
  __syncthreads();
  int e = blockIdx.x*1024 + tid;
  int myd = dstb[e];
  int rank = 0;
  for(int ep=0; ep<e; ep++) rank += (dstb[ep]==myd) ? 1 : 0;
  adjp[off[myd]+rank] = (ei[e] << 13) | e;                          // real edge
  if(blockIdx.x==0) adjp[off[tid+1]-1] = (tid << 13) | (EE + tid);  // self loop last
}

// ---------------- LSTM over T steps, one block per batch ----------------
__global__ __launch_bounds__(256) void k_lstm(
    const float* __restrict__ rain, const float* __restrict__ Wih,
    const float* __restrict__ Whh, const float* __restrict__ bih,
    const float* __restrict__ bhh, float* __restrict__ hs){
  int b = blockIdx.x;
  int j = threadIdx.x;
  __shared__ float h_lds[HRR];
  __shared__ float g_lds[4*HRR];
  float wh[HRR];
  #pragma unroll
  for(int k=0;k<HRR;k++) wh[k] = Whh[j*HRR+k];
  float wi = Wih[j];
  float bias = bih[j] + bhh[j];
  float c = 0.f;
  if(j < HRR) h_lds[j] = 0.f;
  __syncthreads();
  for(int t=0;t<TT;t++){
    float x = rain[b*TT+t];
    float g = fmaf(wi, x, bias);
    #pragma unroll
    for(int k=0;k<HRR;k++) g = fmaf(wh[k], h_lds[k], g);
    g_lds[j] = g;
    __syncthreads();
    if(j < HRR){
      c = sigmoidf_(g_lds[HRR+j])*c + sigmoidf_(g_lds[j])*tanhf(g_lds[2*HRR+j]);
      float h = sigmoidf_(g_lds[3*HRR+j])*tanhf(c);
      h_lds[j] = h;
      hs[(t*BB+b)*HRR + j] = h;
    }
    __syncthreads();
  }
}

// ---------------- runoff = leaky(hs @ fcW^T + fcb), + inflow at node 753 ----------------
__global__ __launch_bounds__(256) void k_runoff(
    const float* __restrict__ hs, const float* __restrict__ fcW,
    const float* __restrict__ fcb, const float* __restrict__ inflow,
    float* __restrict__ runoff, float* __restrict__ lat){
  int p = blockIdx.x;
  int q = p & 3; int tb = p >> 2; int t = tb >> 5; int b = tb & 31;
  int n = q*256 + threadIdx.x;
  __shared__ float hrow[HRR];
  if(threadIdx.x < HRR) hrow[threadIdx.x] = hs[(t*BB+b)*HRR + threadIdx.x];
  __syncthreads();
  const float* wrow = fcW + n*HRR;
  float a0=0,a1=0,a2=0,a3=0;
  #pragma unroll
  for(int k=0;k<HRR;k+=4){
    float4 w = *reinterpret_cast<const float4*>(wrow + k);
    a0 = fmaf(w.x, hrow[k+0], a0);
    a1 = fmaf(w.y, hrow[k+1], a1);
    a2 = fmaf(w.z, hrow[k+2], a2);
    a3 = fmaf(w.w, hrow[k+3], a3);
  }
  float acc = (a0+a1)+(a2+a3) + fcb[n];
  float r = leaky(acc, 0.01f);
  if(n == 753) r += inflow[b*TT + t];
  runoff[(t*BB+b)*NNODE + n] = r;
  lat[(size_t)(b*TT+t)*NNODE + n] = r;
}

// ---------------- GAT1 node prep for t=0 ----------------
__global__ __launch_bounds__(256) void k_prep0(const float* __restrict__ runoff,
    const float* __restrict__ g1W, const float* __restrict__ g1as, const float* __restrict__ g1ad,
    float* __restrict__ h1, float* __restrict__ s1, float* __restrict__ d1){
  int idx = blockIdx.x*256 + threadIdx.x;    // 32768 = B*N
  int b = idx >> 10; int n = idx & 1023;
  float x2 = runoff[b*NNODE + n];            // t=0
  float hv[24];
  size_t base = (size_t)b*NNODE + n;
  #pragma unroll
  for(int o=0;o<24;o++){
    hv[o] = x2*g1W[48+o];
    h1[base*24+o] = hv[o];
  }
  #pragma unroll
  for(int hd=0; hd<NHEAD; hd++){
    float s=0.f, d=0.f;
    #pragma unroll
    for(int c=0;c<3;c++){
      float v = hv[hd*3+c];
      s = fmaf(v, g1as[hd*3+c], s);
      d = fmaf(v, g1ad[hd*3+c], d);
    }
    s1[base*8+hd] = s; d1[base*8+hd] = d;
  }
}

// ---------------- GAT1 edge pass (256 thr, 32 nodes/block) + GAT2 prep ----------------
__global__ __launch_bounds__(256) void k_gat1f(
    const int* __restrict__ adjp, const int* __restrict__ off,
    const float* __restrict__ h1, const float* __restrict__ s1, const float* __restrict__ d1,
    const float* __restrict__ g1b, const float* __restrict__ g2W,
    const float* __restrict__ g2as, const float* __restrict__ g2ad,
    float* __restrict__ h2, float* __restrict__ s2, float* __restrict__ d2,
    float* __restrict__ att, int t){
  int tid = threadIdx.x;
  int g = tid >> 3; int hd = tid & 7;
  int p = blockIdx.x*32 + g;                 // (b,n); all groups in a block share b
  int b = p >> 10; int n = p & 1023;
  __shared__ float ss[NNODE*NHEAD];          // 32 KB: s1 for this b
  __shared__ float x1buf[32][25];
  size_t bbase = (size_t)b*NNODE;
  for(int i=tid; i<NNODE*NHEAD; i+=256) ss[i] = s1[bbase*8 + i];
  __syncthreads();
  int o0 = off[n], o1 = off[n+1];
  float dn = d1[(bbase+n)*8+hd];
  float m = -1e30f, den = 0.f;
  for(int idx=o0; idx<o1; idx++){
    int pk = adjp[idx]; int s = pk >> 13;
    float lg = leaky(ss[s*8+hd] + dn, 0.2f);
    if(lg > m){ den *= expf(m - lg); m = lg; }
    den += expf(lg - m);
  }
  float inv = 1.f/(den + 1e-16f);
  float o_0=0.f, o_1=0.f, o_2=0.f;
  for(int idx=o0; idx<o1; idx++){
    int pk = adjp[idx]; int s = pk >> 13; int eid = pk & 8191;
    float lg = leaky(ss[s*8+hd] + dn, 0.2f);
    float al = expf(lg - m)*inv;
    att[((size_t)(t*BB+b)*NEDGE + eid)*NHEAD + hd] = al;
    const float* hr = h1 + (bbase+s)*24 + hd*3;
    o_0 = fmaf(hr[0], al, o_0);
    o_1 = fmaf(hr[1], al, o_1);
    o_2 = fmaf(hr[2], al, o_2);
  }
  x1buf[g][hd*3+0] = leaky(o_0 + g1b[hd*3+0], 0.01f);
  x1buf[g][hd*3+1] = leaky(o_1 + g1b[hd*3+1], 0.01f);
  x1buf[g][hd*3+2] = leaky(o_2 + g1b[hd*3+2], 0.01f);
  __syncthreads();
  // GAT2 node prep: h2 (16), s2/d2 (8)
  float h2v0=0.f, h2v1=0.f;
  int oA = hd*2, oB = hd*2+1;
  #pragma unroll
  for(int k=0;k<24;k++){
    float xv = x1buf[g][k];
    h2v0 = fmaf(xv, g2W[k*16+oA], h2v0);
    h2v1 = fmaf(xv, g2W[k*16+oB], h2v1);
  }
  h2[(bbase+n)*16+oA] = h2v0;
  h2[(bbase+n)*16+oB] = h2v1;
  s2[(bbase+n)*8+hd] = h2v0*g2as[oA] + h2v1*g2as[oB];
  d2[(bbase+n)*8+hd] = h2v0*g2ad[oA] + h2v1*g2ad[oB];
}

// ---------------- GAT2 edge pass (256 thr, 32 nodes/block) -> xf ----------------
__global__ __launch_bounds__(256) void k_gat2f(
    const int* __restrict__ adjp, const int* __restrict__ off,
    const float* __restrict__ h2, const float* __restrict__ s2, const float* __restrict__ d2,
    const float* __restrict__ g2b, float* __restrict__ xf){
  int tid = threadIdx.x;
  int g = tid >> 3; int hd = tid & 7;
  int p = blockIdx.x*32 + g;
  int b = p >> 10; int n = p & 1023;
  __shared__ float ss[NNODE*NHEAD];          // 32 KB: s2 for this b
  __shared__ float outbuf[32][17];
  size_t bbase = (size_t)b*NNODE;
  for(int i=tid; i<NNODE*NHEAD; i+=256) ss[i] = s2[bbase*8 + i];
  __syncthreads();
  int o0 = off[n], o1 = off[n+1];
  float dn = d2[(bbase+n)*8+hd];
  float m = -1e30f, den = 0.f;
  for(int idx=o0; idx<o1; idx++){
    int pk = adjp[idx]; int s = pk >> 13;
    float lg = leaky(ss[s*8+hd] + dn, 0.2f);
    if(lg > m){ den *= expf(m - lg); m = lg; }
    den += expf(lg - m);
  }
  float inv = 1.f/(den + 1e-16f);
  float o_0=0.f, o_1=0.f;
  for(int idx=o0; idx<o1; idx++){
    int pk = adjp[idx]; int s = pk >> 13;
    float lg = leaky(ss[s*8+hd] + dn, 0.2f);
    float al = expf(lg - m)*inv;
    const float* hr = h2 + (bbase+s)*16 + hd*2;
    o_0 = fmaf(hr[0], al, o_0);
    o_1 = fmaf(hr[1], al, o_1);
  }
  outbuf[g][hd*2+0] = o_0;
  outbuf[g][hd*2+1] = o_1;
  __syncthreads();
  if(hd < 2){
    float acc = 0.f;
    #pragma unroll
    for(int k=0;k<8;k++) acc += outbuf[g][k*2+hd];
    float v = leaky(acc*0.125f + g2b[hd], 0.01f);
    xf[b*TWO_N + n*2 + hd] = v;
  }
}

// ---------------- cell GEMM split-K2 (512 blocks, quadruple j-map) + winner-gate tail ----------------
// block (half, q): rows j = (jl>>1)*512 + q*2 + (jl&1)  => the 8 rows cover gate quadruples for u=2q,2q+1
__global__ __launch_bounds__(256) void k_cellgate(const float* __restrict__ xf,
    const float* __restrict__ hn, const float* __restrict__ Wih, const float* __restrict__ Whh,
    const float* __restrict__ bih, const float* __restrict__ bhh,
    float* __restrict__ gp0, float* __restrict__ gp1,
    float* __restrict__ cn, float* __restrict__ hraw, float* __restrict__ stats,
    int* __restrict__ cnt){
  __shared__ float xl[256*33];
  __shared__ int winner;
  int bid = blockIdx.x;
  int half = bid >> 8; int q = bid & 255;
  int tid = threadIdx.x;
  int jl = tid >> 5; int b = tid & 31;
  int j = (jl>>1)*512 + q*2 + (jl&1);
  float a0=0,a1=0,a2=0,a3=0;
  int kbeg = half*1280, kend = kbeg + 1280;
  for(int k0=kbeg; k0<kend; k0+=256){
    if(k0 < TWO_N){
      for(int i=0;i<32;i++) xl[tid*33+i] = xf[i*TWO_N + k0 + tid];
    } else {
      for(int i=0;i<32;i++) xl[tid*33+i] = hn[i*HLL + (k0-TWO_N) + tid];
    }
    __syncthreads();
    const float* wrow = (k0 < TWO_N) ? (Wih + (size_t)j*TWO_N + k0)
                                     : (Whh + (size_t)j*HLL + (k0-TWO_N));
    #pragma unroll 4
    for(int kk=0; kk<256; kk+=8){
      float4 w0 = *reinterpret_cast<const float4*>(wrow + kk);
      float4 w1 = *reinterpret_cast<const float4*>(wrow + kk + 4);
      const float* xp = &xl[kk*33 + b];
      a0 = fmaf(w0.x, xp[0],   a0);
      a1 = fmaf(w0.y, xp[33],  a1);
      a2 = fmaf(w0.z, xp[66],  a2);
      a3 = fmaf(w0.w, xp[99],  a3);
      a0 = fmaf(w1.x, xp[132], a0);
      a1 = fmaf(w1.y, xp[165], a1);
      a2 = fmaf(w1.z, xp[198], a2);
      a3 = fmaf(w1.w, xp[231], a3);
    }
    __syncthreads();
  }
  float* dst = half ? gp1 : gp0;
  dst[b*TWO_N + j] = (a0+a1)+(a2+a3);
  // ---- winner tail: second-arriving half computes gates for u = 2q, 2q+1 ----
  __threadfence();                                 // release partials
  if(tid==0) winner = atomicAdd(&cnt[q], 1);
  __syncthreads();
  if(winner == 1){
    __threadfence();                               // acquire other half's partials
    float hval = 0.f;
    int r = tid >> 5;                              // reuse jl slot: r = u offset (0/1) for tid<64
    if(tid < 64){
      int u = q*2 + r;
      float gi = gp0[b*TWO_N + u]          + gp1[b*TWO_N + u]          + bih[u]        + bhh[u];
      float gf = gp0[b*TWO_N + HLL + u]    + gp1[b*TWO_N + HLL + u]    + bih[HLL+u]    + bhh[HLL+u];
      float gg = gp0[b*TWO_N + 2*HLL + u]  + gp1[b*TWO_N + 2*HLL + u]  + bih[2*HLL+u]  + bhh[2*HLL+u];
      float go = gp0[b*TWO_N + 3*HLL + u]  + gp1[b*TWO_N + 3*HLL + u]  + bih[3*HLL+u]  + bhh[3*HLL+u];
      float c = sigmoidf_(gf)*cn[b*HLL+u] + sigmoidf_(gi)*tanhf(gg);
      cn[b*HLL+u] = c;
      hval = sigmoidf_(go)*tanhf(c);
      hraw[b*HLL+u] = hval;
    }
    __syncthreads();                               // xl free for reuse
    if(tid < 64){ xl[tid] = hval; xl[64+tid] = hval*hval; }
    __syncthreads();
    if(tid < 32){
      stats[tid*(2*256) + q*2 + 0] = xl[tid] + xl[32+tid];       // sum h over u=2q,2q+1
      stats[tid*(2*256) + q*2 + 1] = xl[64+tid] + xl[96+tid];    // sum h^2
    }
    if(tid==0) atomicSub(&cnt[q], 2);              // RMW-only reset (R9/R10 lesson)
  }
}

// ---------------- LN finalize + lin GEMM + softplus -> pred + fused next-step GAT1 prep ----------------
__global__ __launch_bounds__(256) void k_linln(const float* __restrict__ hraw,
    const float* __restrict__ stats, const float* __restrict__ lng, const float* __restrict__ lnb,
    float* __restrict__ hn,
    const float* __restrict__ W, const float* __restrict__ bias,
    const float* __restrict__ runoff, float* __restrict__ pred,
    float* __restrict__ h1, float* __restrict__ s1, float* __restrict__ d1,
    const float* __restrict__ g1W, const float* __restrict__ g1as, const float* __restrict__ g1ad,
    int t){
  __shared__ float hl[256*33];
  __shared__ float red1[256], red2[256];
  __shared__ float musd[32], rstds[32];
  const int q = blockIdx.x;
  const int tid = threadIdx.x;
  // --- reduce LN stats (coalesced layout stats[b*512 + qq*2 + {0,1}]), fixed order ---
  {
    int b8 = tid >> 3, l8 = tid & 7;
    float s = 0.f, s2 = 0.f;
    for(int qq = l8*32; qq < l8*32+32; qq++){
      s  += stats[b8*512 + qq*2 + 0];
      s2 += stats[b8*512 + qq*2 + 1];
    }
    red1[tid] = s; red2[tid] = s2;
    __syncthreads();
    if(l8 < 4){ red1[tid] += red1[tid+4]; red2[tid] += red2[tid+4]; }
    __syncthreads();
    if(l8 < 2){ red1[tid] += red1[tid+2]; red2[tid] += red2[tid+2]; }
    __syncthreads();
    if(l8 == 0){
      float S = red1[tid] + red1[tid+1];
      float S2 = red2[tid] + red2[tid+1];
      float mu = S * (1.f/HLL);
      float var = S2 * (1.f/HLL) - mu*mu;
      musd[b8] = mu;
      rstds[b8] = rsqrtf(var + 1e-5f);
    }
    __syncthreads();
  }
  // --- write this block's 64-element slice of normalized hn (for next-step cell GEMM) ---
  if(tid < 64){
    int e = q*64 + tid; int b = e >> 9; int u = e & 511;
    hn[e] = (hraw[e] - musd[b])*rstds[b]*lng[u] + lnb[u];
  }
  // --- lin GEMM with LN applied inline at staging ---
  int jl = tid >> 5; int b = tid & 31;
  int j = q*8 + jl;
  float a0=0.f,a1=0.f,a2=0.f,a3=0.f;
  for(int k0=0; k0<HLL; k0+=256){
    float lg_ = lng[k0+tid], lb_ = lnb[k0+tid];
    __syncthreads();
    for(int i=0;i<32;i++)
      hl[tid*33+i] = (hraw[i*HLL + k0 + tid] - musd[i])*rstds[i]*lg_ + lb_;
    __syncthreads();
    const float* wrow = W + (size_t)j*HLL + k0;
    #pragma unroll 4
    for(int kk=0; kk<256; kk+=8){
      float4 w0 = *reinterpret_cast<const float4*>(wrow + kk);
      float4 w1 = *reinterpret_cast<const float4*>(wrow + kk + 4);
      const float* xp = &hl[kk*33 + b];
      a0 = fmaf(w0.x, xp[0],   a0);
      a1 = fmaf(w0.y, xp[33],  a1);
      a2 = fmaf(w0.z, xp[66],  a2);
      a3 = fmaf(w0.w, xp[99],  a3);
      a0 = fmaf(w1.x, xp[132], a0);
      a1 = fmaf(w1.y, xp[165], a1);
      a2 = fmaf(w1.z, xp[198], a2);
      a3 = fmaf(w1.w, xp[231], a3);
    }
  }
  float val = (a0+a1)+(a2+a3) + bias[j];
  float sp = fmaxf(val, 0.f) + log1pf(expf(-fabsf(val)));   // softplus, stable
  pred[((size_t)b*TT + t)*TWO_N + j] = sp;
  if(t+1 < TT){
    float partner = __shfl_xor(sp, 32);   // jl parity swap within wave64, same b
    if((jl & 1) == 0){
      int n = j >> 1;
      float x2 = runoff[(size_t)(t+1)*BB*NNODE + b*NNODE + n];
      float hv2[24];
      size_t base = (size_t)b*NNODE + n;
      #pragma unroll
      for(int o=0;o<24;o++){
        hv2[o] = sp*g1W[o] + partner*g1W[24+o] + x2*g1W[48+o];
        h1[base*24+o] = hv2[o];
      }
      #pragma unroll
      for(int hd=0; hd<NHEAD; hd++){
        float s=0.f, d=0.f;
        #pragma unroll
        for(int c2=0;c2<3;c2++){
          float v2 = hv2[hd*3+c2];
          s = fmaf(v2, g1as[hd*3+c2], s);
          d = fmaf(v2, g1ad[hd*3+c2], d);
        }
        s1[base*8+hd] = s; d1[base*8+hd] = d;
      }
    }
  }
}

// ---------------- init hn/cn to zero ----------------
__global__ __launch_bounds__(512) void k_init(float* __restrict__ hn, float* __restrict__ cn){
  int idx = blockIdx.x*512 + threadIdx.x;   // 32768
  if(idx < BB*HLL) hn[idx] = 0.f;
  else cn[idx - BB*HLL] = 0.f;
}

extern "C" void kernel_launch(void* const* d_in, const int* in_sizes, int n_in,
                              void* d_out, int out_size, void* d_ws, size_t ws_size,
                              hipStream_t stream){
  const float* rainfall  = (const float*)d_in[0];
  const float* inflow    = (const float*)d_in[1];
  const int*   edge_index= (const int*)  d_in[2];
  const float* lstm_Wih  = (const float*)d_in[3];
  const float* lstm_Whh  = (const float*)d_in[4];
  const float* lstm_bih  = (const float*)d_in[5];
  const float* lstm_bhh  = (const float*)d_in[6];
  const float* fc_W      = (const float*)d_in[7];
  const float* fc_b      = (const float*)d_in[8];
  const float* g1_W      = (const float*)d_in[9];
  const float* g1_as     = (const float*)d_in[10];
  const float* g1_ad     = (const float*)d_in[11];
  const float* g1_b      = (const float*)d_in[12];
  const float* g2_W      = (const float*)d_in[13];
  const float* g2_as     = (const float*)d_in[14];
  const float* g2_ad     = (const float*)d_in[15];
  const float* g2_b      = (const float*)d_in[16];
  const float* cell_Wih  = (const float*)d_in[17];
  const float* cell_Whh  = (const float*)d_in[18];
  const float* cell_bih  = (const float*)d_in[19];
  const float* cell_bhh  = (const float*)d_in[20];
  const float* ln_g      = (const float*)d_in[21];
  const float* ln_b      = (const float*)d_in[22];
  const float* lin_W     = (const float*)d_in[23];
  const float* lin_b     = (const float*)d_in[24];

  float* out  = (float*)d_out;
  float* pred = out;                       // (B,T,2N) = 4194304
  float* lat  = out + (size_t)4194304;     // (B,T,N,1) = 2097152
  float* att  = out + (size_t)6291456;     // (T,B,5120,8)

  float* ws = (float*)d_ws;
  float* hs     = ws;                        // 131072
  float* runoff = hs + 131072;               // 2097152
  float* h1     = runoff + 2097152;          // 786432
  float* s1     = h1 + 786432;               // 262144
  float* d1     = s1 + 262144;               // 262144
  float* h2     = d1 + 262144;               // 524288
  float* s2     = h2 + 524288;               // 262144
  float* d2     = s2 + 262144;               // 262144
  float* xfb    = d2 + 262144;               // 65536
  float* gp0    = xfb + 65536;               // 65536
  float* gp1    = gp0 + 65536;               // 65536
  float* hraw   = gp1 + 65536;               // 16384
  float* stats  = hraw + 16384;              // 16384 (32 b x 256 q x 2)
  float* hn     = stats + 16384;             // 16384
  float* cn     = hn + 16384;                // 16384
  int*   off    = (int*)(cn + 16384);        // 1025 (pad 1032)
  int*   adjp   = off + 1032;                // 5120
  int*   cnt    = adjp + 5120;               // 256
  if(ws_size < 19424288ull) return;          // diagnostic: zero output

  hipMemsetAsync(cnt, 0, 256*sizeof(int), stream);
  k_init<<<64, 512, 0, stream>>>(hn, cn);
  k_csr_off<<<1, 1024, 0, stream>>>(edge_index, off);
  k_csr_fill<<<4, 1024, 0, stream>>>(edge_index, off, adjp);
  k_lstm<<<BB, 256, 0, stream>>>(rainfall, lstm_Wih, lstm_Whh, lstm_bih, lstm_bhh, hs);
  k_runoff<<<TT*BB*4, 256, 0, stream>>>(hs, fc_W, fc_b, inflow, runoff, lat);
  k_prep0<<<128, 256, 0, stream>>>(runoff, g1_W, g1_as, g1_ad, h1, s1, d1);

  for(int t=0; t<TT; t++){
    k_gat1f<<<1024, 256, 0, stream>>>(adjp, off, h1, s1, d1,
        g1_b, g2_W, g2_as, g2_ad, h2, s2, d2, att, t);
    k_gat2f<<<1024, 256, 0, stream>>>(adjp, off, h2, s2, d2, g2_b, xfb);
    k_cellgate<<<512, 256, 0, stream>>>(xfb, hn, cell_Wih, cell_Whh,
        cell_bih, cell_bhh, gp0, gp1, cn, hraw, stats, cnt);
    k_linln<<<256, 256, 0, stream>>>(hraw, stats, ln_g, ln_b, hn,
        lin_W, lin_b, runoff, pred, h1, s1, d1, g1_W, g1_as, g1_ad, t);
  }
}